// Round 14
// baseline (139.693 us; speedup 1.0000x reference)
//
#include <hip/hip_runtime.h>

#define NPOS 1024
#define BB   32
#define SS   1024
#define ALPHA_C 0.3f
#define CAP  128      // max source rows per hist row; Poisson(32), P(>128) ~ 0
#define OCAP 1024     // per-batch overflow capacity (cannot be exceeded)
#define MAXO 16       // overflow entries/batch processed by fixup (E~4, P(>16)~1e-6)
#define PADPAIR 0x10001000u   // two packed PRE-SHIFTED pads (byte off 4096 = zero slot)
#define BSTRIDE 1032          // floats per LDS row slot: 1024 data + zero slot @ [1024]

typedef const __attribute__((address_space(1))) unsigned int guint;
typedef __attribute__((address_space(3))) unsigned int luint;

// ---- K0: fast zero-fill of hist (4MB) + cnt (4KB) ----
__global__ __launch_bounds__(256) void zero_fill(float4* __restrict__ p) {
    p[blockIdx.x * 256 + threadIdx.x] = make_float4(0.f, 0.f, 0.f, 0.f);
}

// ---- K1: ONE pass over adds builds row-lists AND the 16-bit column ELL.
// ELL entries are PRE-SHIFTED byte offsets (p2*4); pad = 4096 (zero slot). ----
__global__ __launch_bounds__(1024) void build_tables(
    const int* __restrict__ adds, int* __restrict__ cnt, int* __restrict__ list,
    ushort* __restrict__ ell16, int* __restrict__ ocnt, int* __restrict__ oent) {
    __shared__ int scnt[NPOS];
    __shared__ int so;
    const int b = blockIdx.x, t = threadIdx.x;
    const int c = adds[b * SS + t];
    ((uint2*)ell16)[b * 1024 + t] = make_uint2(PADPAIR, PADPAIR);  // init 8B each
    scnt[t] = 0;
    if (t == 0) so = 0;
    __syncthreads();
    // row-list entry (global cnt zeroed by zero_fill)
    const int rslot = atomicAdd(&cnt[c], 1);
    if (rslot < CAP) list[c * CAP + rslot] = b * SS + t;
    // column ELL entry (pre-shifted byte offset)
    const int slot = atomicAdd(&scnt[c], 1);
    if (slot < 4) {
        ell16[(((size_t)b * 512 + (c & 511)) * 2 + (c >> 9)) * 4 + slot] = (ushort)(t << 2);
    } else {
        const int o = atomicAdd(&so, 1);
        if (o < OCAP) oent[b * OCAP + o] = (c << 10) | t;        // pack (c,p2) RAW
    }
    __syncthreads();
    if (t == 0) ocnt[b] = (so < OCAP) ? so : OCAP;
}

// ---- K1c: overflow fixup — rare (~120 total) entries via global atomics
// into the zeroed hist, BEFORE hist_rows adds its sums on top. ----
__global__ __launch_bounds__(256) void overflow_fixup(
    const float* __restrict__ a, const int* __restrict__ adds,
    const int* __restrict__ ocnt, const int* __restrict__ oent,
    float* __restrict__ hist) {
    const int b  = blockIdx.x;
    const int ei = blockIdx.y;
    if (ei >= ocnt[b]) return;
    const int e  = oent[b * OCAP + ei];
    const int c  = e >> 10, p2 = e & 1023;
    const int p1 = blockIdx.z * 256 + threadIdx.x;
    const int r  = adds[b * SS + p1];
    const float v = a[((size_t)(b * SS + p1)) * SS + p2];
    atomicAdd(&hist[(size_t)r * NPOS + c], v);
}

// ---- K2: block per hist row r; 512 threads own columns t and t+512.
// TRIPLE-buffered DMA staging with COUNTED vmcnt(2): row k+2's global_load_lds
// is issued at iter k and only required complete at iter k+1's barrier — the
// L3 latency gets two full gather phases to hide under (T3/T4 pattern).
// lsrc rolled through registers; ELL holds pre-shifted byte offsets. ----
__global__ __launch_bounds__(512) void hist_rows_kernel(
    const float* __restrict__ a, const int* __restrict__ rowcnt,
    const int* __restrict__ rowlist, const ushort* __restrict__ ell16,
    float* __restrict__ hist) {
    __shared__ float bufflat[3 * BSTRIDE];
    __shared__ int   lsrc[CAP];
    const int r = blockIdx.x, t = threadIdx.x;
    const int w = t >> 6, lane = t & 63;

    int n = rowcnt[r]; if (n > CAP) n = CAP;
    if (t < CAP && t < n) lsrc[t] = rowlist[r * CAP + t];
    if (t < 3) bufflat[t * BSTRIDE + 1024] = 0.f;      // zero slots (pad target)
    __syncthreads();

    const uint4* ellv = (const uint4*)ell16;   // [b*512 + t] = cols (t, t+512)
    float acc0 = 0.f, acc1 = 0.f;
    uint4 E = make_uint4(PADPAIR, PADPAIR, PADPAIR, PADPAIR);
    int s1 = 0, s2 = 0;

    if (n > 0) {
        E = ellv[(size_t)(lsrc[0] >> 10) * 512 + t];
        if (w < 4) {
            guint* gp = (guint*)(a + (size_t)lsrc[0] * SS + (w << 8) + (lane << 2));
            luint* lp = (luint*)(void*)&bufflat[0 * BSTRIDE + (w << 8)];
            __builtin_amdgcn_global_load_lds(gp, lp, 16, 0, 0);
        }
        if (n > 1) {
            s1 = lsrc[1];
            if (w < 4) {
                guint* gp = (guint*)(a + (size_t)s1 * SS + (w << 8) + (lane << 2));
                luint* lp = (luint*)(void*)&bufflat[1 * BSTRIDE + (w << 8)];
                __builtin_amdgcn_global_load_lds(gp, lp, 16, 0, 0);
            }
        }
        if (n > 2) s2 = lsrc[2];
    }
    // one-time full drain (rows 0 and 1 staged, E loaded), then enter the loop
    asm volatile("s_waitcnt vmcnt(0)" ::: "memory");
    __builtin_amdgcn_s_barrier();

    int cur = 0;
    for (int k = 0; k < n; ++k) {
        // issue DMA for row k+2 (two iterations to land)
        int nx = cur + 2; if (nx >= 3) nx -= 3;
        if (k + 2 < n && w < 4) {
            guint* gp = (guint*)(a + (size_t)s2 * SS + (w << 8) + (lane << 2));
            luint* lp = (luint*)(void*)&bufflat[nx * BSTRIDE + (w << 8)];
            __builtin_amdgcn_global_load_lds(gp, lp, 16, 0, 0);
        }
        // prefetch ELL indices for row k+1 (consumed next iteration)
        uint4 F = make_uint4(PADPAIR, PADPAIR, PADPAIR, PADPAIR);
        if (k + 1 < n) F = ellv[(size_t)(s1 >> 10) * 512 + t];
        __builtin_amdgcn_sched_barrier(0);

        // gather row k from bufflat[cur] (pure LDS + VALU; offsets pre-shifted)
        const char* rb = (const char*)(bufflat + cur * BSTRIDE);
        acc0 += *(const float*)(rb + (E.x & 0xffffu));
        acc0 += *(const float*)(rb + (E.x >> 16));
        acc0 += *(const float*)(rb + (E.y & 0xffffu));
        acc0 += *(const float*)(rb + (E.y >> 16));
        acc1 += *(const float*)(rb + (E.z & 0xffffu));
        acc1 += *(const float*)(rb + (E.z >> 16));
        acc1 += *(const float*)(rb + (E.w & 0xffffu));
        acc1 += *(const float*)(rb + (E.w >> 16));
        // roll the lsrc pipeline (read-only LDS; no hazard)
        s1 = s2;
        s2 = (k + 3 < n) ? lsrc[k + 3] : 0;
        __builtin_amdgcn_sched_barrier(0);

        // counted drain: DMA(k+2) + ELL(k+1) stay in flight; DMA(k+1) guaranteed done
        asm volatile("s_waitcnt vmcnt(2)" ::: "memory");
        __builtin_amdgcn_s_barrier();
        E = F;
        cur = cur + 1; if (cur >= 3) cur -= 3;
    }

    const size_t o0 = (size_t)r * NPOS + t;
    const float base0 = hist[o0], base1 = hist[o0 + 512];   // fixup contributions
    hist[o0]       = 1.f / (1.f + __expf(-(base0 + acc0)));
    hist[o0 + 512] = 1.f / (1.f + __expf(-(base1 + acc1)));
}

// ---- K3: out = s + 0.3 * score[pos[b,p1]*1024 + pos[b,p2]] ----
__global__ __launch_bounds__(256) void gather_kernel(
    const float* __restrict__ s, const int* __restrict__ pos,
    const float* __restrict__ score, float* __restrict__ out) {
    const int row = blockIdx.x;
    const int b   = row >> 10;
    const int*  posb = pos + b * SS;
    const int   base = posb[row & 1023] * NPOS;
    const size_t off = (size_t)row * SS;

    const int t = threadIdx.x;
    float4 v = ((const float4*)(s + off))[t];
    int4   c = ((const int4*)posb)[t];
    float4 o;
    o.x = v.x + ALPHA_C * score[base + c.x];
    o.y = v.y + ALPHA_C * score[base + c.y];
    o.z = v.z + ALPHA_C * score[base + c.z];
    o.w = v.w + ALPHA_C * score[base + c.w];
    ((float4*)(out + off))[t] = o;
}

extern "C" void kernel_launch(void* const* d_in, const int* in_sizes, int n_in,
                              void* d_out, int out_size, void* d_ws, size_t ws_size,
                              hipStream_t stream) {
    const float* s_arc = (const float*)d_in[0];
    const float* a_arc = (const float*)d_in[1];
    const int*   adds  = (const int*)d_in[2];
    const int*   pos   = (const int*)d_in[3];
    float* out  = (float*)d_out;

    // ws layout: [hist 4MB][cnt 4KB][list 512KB][ell16 256KB][ocnt 128B][oent 128KB]
    float*  hist  = (float*)d_ws;
    int*    cnt   = (int*)((char*)d_ws + (size_t)NPOS * NPOS * sizeof(float));
    int*    list  = cnt + NPOS;
    ushort* ell16 = (ushort*)(list + NPOS * CAP);
    int*    ocnt  = (int*)(ell16 + (size_t)BB * NPOS * 4);
    int*    oent  = ocnt + BB;

    // hist (4MB) + cnt (4KB): 1025 blocks x 256 thr x 16B exactly
    zero_fill<<<1025, 256, 0, stream>>>((float4*)hist);
    build_tables<<<BB, 1024, 0, stream>>>(adds, cnt, list, ell16, ocnt, oent);
    overflow_fixup<<<dim3(BB, MAXO, SS / 256), 256, 0, stream>>>(a_arc, adds, ocnt, oent, hist);
    hist_rows_kernel<<<NPOS, 512, 0, stream>>>(a_arc, cnt, list, ell16, hist);
    gather_kernel<<<BB * SS, 256, 0, stream>>>(s_arc, pos, hist, out);
}

// Round 15
// 132.747 us; speedup vs baseline: 1.0523x; 1.0523x over previous
//
#include <hip/hip_runtime.h>

#define NPOS 1024
#define BB   32
#define SS   1024
#define ALPHA_C 0.3f
#define OCAP 1024     // per-batch overflow capacity per side (cannot be exceeded)
#define MAXO 16       // overflow entries/batch/side processed by fixup (mean ~3.7)
#define PADPAIR 0x10001000u   // two packed PRE-SHIFTED pads (byte off 4096 = zero slot)
#define SSTRIDE 1026          // floats per S row: 1024 data + zero slot @ [1024] + align

// ---- K0: zero hist (4MB) + rcnt (128KB) + bmask (4KB) = 1057 * 4KB ----
__global__ __launch_bounds__(256) void zero_fill(float4* __restrict__ p) {
    p[blockIdx.x * 256 + threadIdx.x] = make_float4(0.f, 0.f, 0.f, 0.f);
}

// ---- K1: one pass over adds builds per-(r,b) row lists (W=4 + row overflow)
// AND the per-batch 16-bit column ELL (W=4 + col overflow). ----
__global__ __launch_bounds__(1024) void build_tables(
    const int* __restrict__ adds, unsigned* __restrict__ rcnt,
    unsigned* __restrict__ bmask, ushort* __restrict__ list,
    ushort* __restrict__ ell16, int* __restrict__ ocntc, int* __restrict__ ocntr,
    int* __restrict__ oentc, int* __restrict__ oentr) {
    __shared__ int scnt[NPOS];
    __shared__ int soc, sor;
    const int b = blockIdx.x, t = threadIdx.x;
    const int c = adds[b * SS + t];   // row-key of p1=t AND column-key of p2=t
    ((uint2*)ell16)[b * 1024 + t] = make_uint2(PADPAIR, PADPAIR);
    scnt[t] = 0;
    if (t == 0) { soc = 0; sor = 0; }
    __syncthreads();
    // column side (pre-shifted byte offsets)
    const int slot = atomicAdd(&scnt[c], 1);
    if (slot < 4) {
        ell16[(((size_t)b * 512 + (c & 511)) * 2 + (c >> 9)) * 4 + slot] = (ushort)(t << 2);
    } else {
        const int o = atomicAdd(&soc, 1);
        if (o < OCAP) oentc[b * OCAP + o] = (c << 10) | t;
    }
    // row side (per-(r,b) W=4 list)
    const unsigned rs = atomicAdd(&rcnt[c * BB + b], 1u);
    if (rs < 4) {
        list[(size_t)c * 128 + b * 4 + rs] = (ushort)t;
    } else {
        const int o = atomicAdd(&sor, 1);
        if (o < OCAP) oentr[b * OCAP + o] = (c << 10) | t;
        atomicOr(&bmask[b * 32 + (t >> 5)], 1u << (t & 31));
    }
    __syncthreads();
    if (t == 0) { ocntc[b] = min(soc, OCAP); ocntr[b] = min(sor, OCAP); }
}

// ---- K1c: fixups into zeroed hist (before hist_rows adds on top).
// y<MAXO: col-ovf entry (all p1 EXCEPT row-ovf); y>=MAXO: row-ovf entry (all p2). ----
__global__ __launch_bounds__(256) void fixup(
    const float* __restrict__ a, const int* __restrict__ adds,
    const int* __restrict__ ocntc, const int* __restrict__ oentc,
    const int* __restrict__ ocntr, const int* __restrict__ oentr,
    const unsigned* __restrict__ bmask, float* __restrict__ hist) {
    const int b = blockIdx.x;
    int y = blockIdx.y;
    const int p = blockIdx.z * 256 + threadIdx.x;
    if (y < MAXO) {                    // column overflow: p is p1
        if (y >= ocntc[b]) return;
        const int e = oentc[b * OCAP + y];
        const int c = e >> 10, p2 = e & 1023;
        if ((bmask[b * 32 + (p >> 5)] >> (p & 31)) & 1u) return;  // row-ovf p1 excluded
        const int r = adds[b * SS + p];
        atomicAdd(&hist[(size_t)r * NPOS + c], a[((size_t)(b * SS + p)) * SS + p2]);
    } else {                           // row overflow: p is p2
        y -= MAXO;
        if (y >= ocntr[b]) return;
        const int e = oentr[b * OCAP + y];
        const int r = e >> 10, p1 = e & 1023;
        const int c = adds[b * SS + p];
        atomicAdd(&hist[(size_t)r * NPOS + c], a[((size_t)(b * SS + p1)) * SS + p]);
    }
}

// ---- K2: block per hist row r; iterate ACTIVE batches only (~20 of 32).
// Per batch: pre-sum its <=4 source rows in registers (coalesced float2 loads),
// ds_write ONE combined row S, scatter S once via the batch's column ELL.
// Loads for batch j+2 issued at iter j; lgkm-only barrier per iter. ----
__global__ __launch_bounds__(512) void hist_rows_kernel(
    const float* __restrict__ a, const unsigned* __restrict__ rcnt,
    const ushort* __restrict__ list, const ushort* __restrict__ ell16,
    float* __restrict__ hist) {
    __shared__ float Sbuf[2][SSTRIDE];   // [..][1024] = 0.0f pad slot
    __shared__ ushort lsrc[128];
    __shared__ int   mcnt_s[32];
    __shared__ ushort actb_s[32];
    __shared__ int   na_s;
    const int r = blockIdx.x, t = threadIdx.x;

    if (t < 128) lsrc[t] = list[(size_t)r * 128 + t];
    if (t < 32)  mcnt_s[t] = min((int)rcnt[r * BB + t], 4);
    if (t < 2)   Sbuf[t][1024] = 0.f;
    __syncthreads();
    if (t == 0) {
        int na = 0;
        for (int b = 0; b < 32; ++b) if (mcnt_s[b]) actb_s[na++] = (ushort)b;
        na_s = na;
    }
    __syncthreads();
    const int na = na_s;
    const uint4* ellv = (const uint4*)ell16;
    float acc0 = 0.f, acc1 = 0.f;
    uint4 E = make_uint4(PADPAIR, PADPAIR, PADPAIR, PADPAIR), F = E;
    float2 R0 = make_float2(0.f, 0.f), R1 = R0, R2 = R0, R3 = R0;
    int mNext = 0;

#define ROWP(bb, s) ((const float2*)(a + ((((size_t)(bb) << 10) + lsrc[(bb) * 4 + (s)]) << 10)) + t)

    if (na > 0) {
        const int b0 = actb_s[0], m0 = mcnt_s[b0];
        E = ellv[(size_t)b0 * 512 + t];
        float2 S = *ROWP(b0, 0);
        if (m0 > 1) { float2 x = *ROWP(b0, 1); S.x += x.x; S.y += x.y; }
        if (m0 > 2) { float2 x = *ROWP(b0, 2); S.x += x.x; S.y += x.y; }
        if (m0 > 3) { float2 x = *ROWP(b0, 3); S.x += x.x; S.y += x.y; }
        ((float2*)&Sbuf[0][0])[t] = S;
        if (na > 1) {
            const int b1 = actb_s[1];
            mNext = mcnt_s[b1];
            F = ellv[(size_t)b1 * 512 + t];
            R0 = *ROWP(b1, 0);
            if (mNext > 1) R1 = *ROWP(b1, 1);
            if (mNext > 2) R2 = *ROWP(b1, 2);
            if (mNext > 3) R3 = *ROWP(b1, 3);
        }
    }
    asm volatile("s_waitcnt lgkmcnt(0)" ::: "memory");
    __builtin_amdgcn_s_barrier();

    for (int j = 0; j < na; ++j) {
        // issue loads for batch j+2 (two iterations to land)
        float2 T0 = make_float2(0.f, 0.f), T1 = T0, T2 = T0, T3 = T0;
        uint4 TE = make_uint4(PADPAIR, PADPAIR, PADPAIR, PADPAIR);
        int mIn = 0;
        if (j + 2 < na) {
            const int b2 = actb_s[j + 2];
            mIn = mcnt_s[b2];
            TE = ellv[(size_t)b2 * 512 + t];
            T0 = *ROWP(b2, 0);
            if (mIn > 1) T1 = *ROWP(b2, 1);
            if (mIn > 2) T2 = *ROWP(b2, 2);
            if (mIn > 3) T3 = *ROWP(b2, 3);
        }
        // pre-sum & write S for batch j+1 (R* loaded one full iteration ago)
        if (j + 1 < na) {
            float2 S = R0;
            if (mNext > 1) { S.x += R1.x; S.y += R1.y; }
            if (mNext > 2) { S.x += R2.x; S.y += R2.y; }
            if (mNext > 3) { S.x += R3.x; S.y += R3.y; }
            ((float2*)&Sbuf[(j + 1) & 1][0])[t] = S;
        }
        // scatter batch j from Sbuf[j&1] (8 LDS reads/thread, pre-shifted offsets)
        const char* rb = (const char*)&Sbuf[j & 1][0];
        acc0 += *(const float*)(rb + (E.x & 0xffffu));
        acc0 += *(const float*)(rb + (E.x >> 16));
        acc0 += *(const float*)(rb + (E.y & 0xffffu));
        acc0 += *(const float*)(rb + (E.y >> 16));
        acc1 += *(const float*)(rb + (E.z & 0xffffu));
        acc1 += *(const float*)(rb + (E.z >> 16));
        acc1 += *(const float*)(rb + (E.w & 0xffffu));
        acc1 += *(const float*)(rb + (E.w >> 16));
        // roll pipeline
        E = F; F = TE;
        R0 = T0; R1 = T1; R2 = T2; R3 = T3; mNext = mIn;
        __builtin_amdgcn_sched_barrier(0);
        // lgkm drain (S-write visibility + scatter reads); vm loads span the barrier
        asm volatile("s_waitcnt lgkmcnt(0)" ::: "memory");
        __builtin_amdgcn_s_barrier();
    }
#undef ROWP

    const size_t o0 = (size_t)r * NPOS + t;
    const float base0 = hist[o0], base1 = hist[o0 + 512];   // fixup contributions
    hist[o0]       = 1.f / (1.f + __expf(-(base0 + acc0)));
    hist[o0 + 512] = 1.f / (1.f + __expf(-(base1 + acc1)));
}

// ---- K3: out = s + 0.3 * score[pos[b,p1]*1024 + pos[b,p2]] ----
__global__ __launch_bounds__(256) void gather_kernel(
    const float* __restrict__ s, const int* __restrict__ pos,
    const float* __restrict__ score, float* __restrict__ out) {
    const int row = blockIdx.x;
    const int b   = row >> 10;
    const int*  posb = pos + b * SS;
    const int   base = posb[row & 1023] * NPOS;
    const size_t off = (size_t)row * SS;

    const int t = threadIdx.x;
    float4 v = ((const float4*)(s + off))[t];
    int4   c = ((const int4*)posb)[t];
    float4 o;
    o.x = v.x + ALPHA_C * score[base + c.x];
    o.y = v.y + ALPHA_C * score[base + c.y];
    o.z = v.z + ALPHA_C * score[base + c.z];
    o.w = v.w + ALPHA_C * score[base + c.w];
    ((float4*)(out + off))[t] = o;
}

extern "C" void kernel_launch(void* const* d_in, const int* in_sizes, int n_in,
                              void* d_out, int out_size, void* d_ws, size_t ws_size,
                              hipStream_t stream) {
    const float* s_arc = (const float*)d_in[0];
    const float* a_arc = (const float*)d_in[1];
    const int*   adds  = (const int*)d_in[2];
    const int*   pos   = (const int*)d_in[3];
    float* out  = (float*)d_out;

    // ws layout:
    // [hist 4MB][rcnt 128KB][bmask 4KB][list 256KB][ell16 256KB]
    // [ocntc 128B][ocntr 128B][oentc 128KB][oentr 128KB]   (~4.9MB total)
    char* w = (char*)d_ws;
    float*    hist  = (float*)w;                 w += (size_t)NPOS * NPOS * 4;
    unsigned* rcnt  = (unsigned*)w;              w += (size_t)NPOS * BB * 4;
    unsigned* bmask = (unsigned*)w;              w += (size_t)BB * 32 * 4;
    ushort*   list  = (ushort*)w;                w += (size_t)NPOS * 128 * 2;
    ushort*   ell16 = (ushort*)w;                w += (size_t)BB * NPOS * 4 * 2;
    int*      ocntc = (int*)w;                   w += BB * 4;
    int*      ocntr = (int*)w;                   w += BB * 4;
    int*      oentc = (int*)w;                   w += (size_t)BB * OCAP * 4;
    int*      oentr = (int*)w;

    // hist + rcnt + bmask contiguous: 1057 blocks x 256 thr x 16B exactly
    zero_fill<<<1057, 256, 0, stream>>>((float4*)hist);
    build_tables<<<BB, 1024, 0, stream>>>(adds, rcnt, bmask, list, ell16,
                                          ocntc, ocntr, oentc, oentr);
    fixup<<<dim3(BB, 2 * MAXO, SS / 256), 256, 0, stream>>>(a_arc, adds, ocntc, oentc,
                                                            ocntr, oentr, bmask, hist);
    hist_rows_kernel<<<NPOS, 512, 0, stream>>>(a_arc, rcnt, list, ell16, hist);
    gather_kernel<<<BB * SS, 256, 0, stream>>>(s_arc, pos, hist, out);
}

// Round 17
// 131.662 us; speedup vs baseline: 1.0610x; 1.0082x over previous
//
#include <hip/hip_runtime.h>

#define NPOS 1024
#define BB   32
#define SS   1024
#define ALPHA_C 0.3f
#define OCAP 256      // per-batch overflow capacity per side (mean ~3.7, P(>256)~0)
#define MAXO 16       // overflow entries/batch/side processed by fixup
#define PADPAIR 0x10001000u   // two packed PRE-SHIFTED pads (byte off 4096 = zero slot)
#define SSTRIDE 1026          // floats per S row: 1024 data + zero slot @ [1024] + align
#define NZ4 16656             // uint4s in the zero region (rcnt+scnt+bmask+ocnt*)
#define NP4 16384             // uint4s in ell16 (PADPAIR init)

typedef float    __attribute__((ext_vector_type(2))) f32x2;
typedef float    __attribute__((ext_vector_type(4))) f32x4;
typedef int      __attribute__((ext_vector_type(4))) i32x4;
typedef unsigned __attribute__((ext_vector_type(4))) u32x4;

// ---- K0: one fill kernel: zeros the counter region, PADPAIR-inits the ELL ----
__global__ __launch_bounds__(256) void fill_tables(u32x4* __restrict__ z,
                                                   u32x4* __restrict__ p) {
    const int i = blockIdx.x * 256 + threadIdx.x;
    if (i < NZ4) z[i] = (u32x4){0u, 0u, 0u, 0u};
    else { const int j = i - NZ4; if (j < NP4) p[j] = (u32x4){PADPAIR, PADPAIR, PADPAIR, PADPAIR}; }
}

// ---- K1: whole-chip build (128 blocks x 256): per-(r,b) row lists (W=4 + ovf)
// and per-batch 16-bit column ELL (W=4 + ovf), via global-atomic counters. ----
__global__ __launch_bounds__(256) void build_tables(
    const int* __restrict__ adds, unsigned* __restrict__ rcnt,
    unsigned* __restrict__ scnt, unsigned* __restrict__ bmask,
    ushort* __restrict__ list, ushort* __restrict__ ell16,
    int* __restrict__ ocntc, int* __restrict__ ocntr,
    int* __restrict__ oentc, int* __restrict__ oentr) {
    const int b  = blockIdx.x >> 2;
    const int tg = ((blockIdx.x & 3) << 8) | threadIdx.x;   // p1 / p2 position
    const int c  = adds[b * SS + tg];
    // column side (pre-shifted byte offsets)
    const unsigned slot = atomicAdd(&scnt[b * NPOS + c], 1u);
    if (slot < 4u) {
        ell16[(((size_t)b * 512 + (c & 511)) * 2 + (c >> 9)) * 4 + slot] = (ushort)(tg << 2);
    } else {
        const int o = atomicAdd(&ocntc[b], 1);
        if (o < OCAP) oentc[b * OCAP + o] = (c << 10) | tg;
    }
    // row side (per-(r,b) W=4 list)
    const unsigned rs = atomicAdd(&rcnt[c * BB + b], 1u);
    if (rs < 4u) {
        list[(size_t)c * 128 + b * 4 + rs] = (ushort)tg;
    } else {
        const int o = atomicAdd(&ocntr[b], 1);
        if (o < OCAP) oentr[b * OCAP + o] = (c << 10) | tg;
        atomicOr(&bmask[b * 32 + (tg >> 5)], 1u << (tg & 31));
    }
}

// ---- K2: block per hist row r; iterate ACTIVE batches (~20 of 32).
// Pre-sum <=4 source rows in registers (nt f32x2 loads), ds_write ONE combined
// row S, scatter once via the batch's column ELL. Writes RAW sums (no base
// read, no sigmoid — fixup adds after, gather applies sigmoid). ----
__global__ __launch_bounds__(512) void hist_rows_kernel(
    const float* __restrict__ a, const unsigned* __restrict__ rcnt,
    const ushort* __restrict__ list, const ushort* __restrict__ ell16,
    float* __restrict__ hist) {
    __shared__ float Sbuf[2][SSTRIDE];   // [..][1024] = 0.0f pad slot
    __shared__ ushort lsrc[128];
    __shared__ int   mcnt_s[32];
    __shared__ ushort actb_s[32];
    __shared__ int   na_s;
    const int r = blockIdx.x, t = threadIdx.x;

    if (t < 128) lsrc[t] = list[(size_t)r * 128 + t];
    if (t < 32)  mcnt_s[t] = min((int)rcnt[r * BB + t], 4);
    if (t < 2)   Sbuf[t][1024] = 0.f;
    __syncthreads();
    if (t == 0) {
        int na = 0;
        for (int b = 0; b < 32; ++b) if (mcnt_s[b]) actb_s[na++] = (ushort)b;
        na_s = na;
    }
    __syncthreads();
    const int na = na_s;
    const u32x4* ellv = (const u32x4*)ell16;
    float acc0 = 0.f, acc1 = 0.f;
    u32x4 E = (u32x4){PADPAIR, PADPAIR, PADPAIR, PADPAIR}, F = E;
    f32x2 R0 = (f32x2){0.f, 0.f}, R1 = R0, R2 = R0, R3 = R0;
    int mNext = 0;

#define ROWP(bb, s) ((const f32x2*)(a + ((((size_t)(bb) << 10) + lsrc[(bb) * 4 + (s)]) << 10)) + t)

    if (na > 0) {
        const int b0 = actb_s[0], m0 = mcnt_s[b0];
        E = ellv[(size_t)b0 * 512 + t];
        f32x2 S = __builtin_nontemporal_load(ROWP(b0, 0));
        if (m0 > 1) S += __builtin_nontemporal_load(ROWP(b0, 1));
        if (m0 > 2) S += __builtin_nontemporal_load(ROWP(b0, 2));
        if (m0 > 3) S += __builtin_nontemporal_load(ROWP(b0, 3));
        ((f32x2*)&Sbuf[0][0])[t] = S;
        if (na > 1) {
            const int b1 = actb_s[1];
            mNext = mcnt_s[b1];
            F = ellv[(size_t)b1 * 512 + t];
            R0 = __builtin_nontemporal_load(ROWP(b1, 0));
            if (mNext > 1) R1 = __builtin_nontemporal_load(ROWP(b1, 1));
            if (mNext > 2) R2 = __builtin_nontemporal_load(ROWP(b1, 2));
            if (mNext > 3) R3 = __builtin_nontemporal_load(ROWP(b1, 3));
        }
    }
    asm volatile("s_waitcnt lgkmcnt(0)" ::: "memory");
    __builtin_amdgcn_s_barrier();

    for (int j = 0; j < na; ++j) {
        // issue loads for batch j+2 (two iterations to land)
        f32x2 T0 = (f32x2){0.f, 0.f}, T1 = T0, T2 = T0, T3 = T0;
        u32x4 TE = (u32x4){PADPAIR, PADPAIR, PADPAIR, PADPAIR};
        int mIn = 0;
        if (j + 2 < na) {
            const int b2 = actb_s[j + 2];
            mIn = mcnt_s[b2];
            TE = ellv[(size_t)b2 * 512 + t];
            T0 = __builtin_nontemporal_load(ROWP(b2, 0));
            if (mIn > 1) T1 = __builtin_nontemporal_load(ROWP(b2, 1));
            if (mIn > 2) T2 = __builtin_nontemporal_load(ROWP(b2, 2));
            if (mIn > 3) T3 = __builtin_nontemporal_load(ROWP(b2, 3));
        }
        // pre-sum & write S for batch j+1 (R* loaded one full iteration ago)
        if (j + 1 < na) {
            f32x2 S = R0;
            if (mNext > 1) S += R1;
            if (mNext > 2) S += R2;
            if (mNext > 3) S += R3;
            ((f32x2*)&Sbuf[(j + 1) & 1][0])[t] = S;
        }
        // scatter batch j from Sbuf[j&1] (8 LDS reads/thread, pre-shifted offsets)
        const char* rb = (const char*)&Sbuf[j & 1][0];
        acc0 += *(const float*)(rb + (E.x & 0xffffu));
        acc0 += *(const float*)(rb + (E.x >> 16));
        acc0 += *(const float*)(rb + (E.y & 0xffffu));
        acc0 += *(const float*)(rb + (E.y >> 16));
        acc1 += *(const float*)(rb + (E.z & 0xffffu));
        acc1 += *(const float*)(rb + (E.z >> 16));
        acc1 += *(const float*)(rb + (E.w & 0xffffu));
        acc1 += *(const float*)(rb + (E.w >> 16));
        // roll pipeline
        E = F; F = TE;
        R0 = T0; R1 = T1; R2 = T2; R3 = T3; mNext = mIn;
        __builtin_amdgcn_sched_barrier(0);
        asm volatile("s_waitcnt lgkmcnt(0)" ::: "memory");
        __builtin_amdgcn_s_barrier();
    }
#undef ROWP

    const size_t o0 = (size_t)r * NPOS + t;
    hist[o0]       = acc0;     // RAW sums; fixup atomics add after; gather sigmoids
    hist[o0 + 512] = acc1;
}

// ---- K2b: fixups via global atomics AFTER hist_rows (raw domain).
// y<MAXO: col-ovf entry (all p1 EXCEPT row-ovf p1); y>=MAXO: row-ovf (all p2). ----
__global__ __launch_bounds__(256) void fixup(
    const float* __restrict__ a, const int* __restrict__ adds,
    const int* __restrict__ ocntc, const int* __restrict__ oentc,
    const int* __restrict__ ocntr, const int* __restrict__ oentr,
    const unsigned* __restrict__ bmask, float* __restrict__ hist) {
    const int b = blockIdx.x;
    int y = blockIdx.y;
    const int p = blockIdx.z * 256 + threadIdx.x;
    if (y < MAXO) {                    // column overflow: p is p1
        if (y >= ocntc[b]) return;
        const int e = oentc[b * OCAP + y];
        const int c = e >> 10, p2 = e & 1023;
        if ((bmask[b * 32 + (p >> 5)] >> (p & 31)) & 1u) return;  // row-ovf p1 excluded
        const int r = adds[b * SS + p];
        atomicAdd(&hist[(size_t)r * NPOS + c], a[((size_t)(b * SS + p)) * SS + p2]);
    } else {                           // row overflow: p is p2
        y -= MAXO;
        if (y >= ocntr[b]) return;
        const int e = oentr[b * OCAP + y];
        const int r = e >> 10, p1 = e & 1023;
        const int c = adds[b * SS + p];
        atomicAdd(&hist[(size_t)r * NPOS + c], a[((size_t)(b * SS + p1)) * SS + p]);
    }
}

// ---- K3: out = s + 0.3 * sigmoid(hist_raw[pos[b,p1]*1024 + pos[b,p2]]).
// nt loads for s (streamed once), nt stores for out -> keeps L2 for the
// 4MB score table + index tables. ----
__global__ __launch_bounds__(256) void gather_kernel(
    const float* __restrict__ s, const int* __restrict__ pos,
    const float* __restrict__ score, float* __restrict__ out) {
    const int row = blockIdx.x;
    const int b   = row >> 10;
    const int*  posb = pos + b * SS;
    const int   base = posb[row & 1023] * NPOS;
    const size_t off = (size_t)row * SS;

    const int t = threadIdx.x;
    f32x4 v = __builtin_nontemporal_load(((const f32x4*)(s + off)) + t);
    i32x4 c = ((const i32x4*)posb)[t];
    const float h0 = score[base + c.x], h1 = score[base + c.y];
    const float h2 = score[base + c.z], h3 = score[base + c.w];
    f32x4 o;
    o.x = v.x + ALPHA_C * (1.f / (1.f + __expf(-h0)));
    o.y = v.y + ALPHA_C * (1.f / (1.f + __expf(-h1)));
    o.z = v.z + ALPHA_C * (1.f / (1.f + __expf(-h2)));
    o.w = v.w + ALPHA_C * (1.f / (1.f + __expf(-h3)));
    __builtin_nontemporal_store(o, ((f32x4*)(out + off)) + t);
}

extern "C" void kernel_launch(void* const* d_in, const int* in_sizes, int n_in,
                              void* d_out, int out_size, void* d_ws, size_t ws_size,
                              hipStream_t stream) {
    const float* s_arc = (const float*)d_in[0];
    const float* a_arc = (const float*)d_in[1];
    const int*   adds  = (const int*)d_in[2];
    const int*   pos   = (const int*)d_in[3];
    float* out  = (float*)d_out;

    // ws layout (bytes):
    // [hist 4MB][rcnt 128K][scnt 128K][bmask 4K][ocntc 128][ocntr 128]
    // [list 256K][ell16 256K][oentc 32K][oentr 32K]  (~4.83MB)
    char* w = (char*)d_ws;
    float*    hist  = (float*)w;                 w += (size_t)NPOS * NPOS * 4;
    unsigned* rcnt  = (unsigned*)w;              w += (size_t)NPOS * BB * 4;
    unsigned* scnt  = (unsigned*)w;              w += (size_t)BB * NPOS * 4;
    unsigned* bmask = (unsigned*)w;              w += (size_t)BB * 32 * 4;
    int*      ocntc = (int*)w;                   w += BB * 4;
    int*      ocntr = (int*)w;                   w += BB * 4;
    ushort*   list  = (ushort*)w;                w += (size_t)NPOS * 128 * 2;
    ushort*   ell16 = (ushort*)w;                w += (size_t)BB * NPOS * 4 * 2;
    int*      oentc = (int*)w;                   w += (size_t)BB * OCAP * 4;
    int*      oentr = (int*)w;

    // zero region = rcnt..ocntr (266496 B = NZ4 uint4s, contiguous after hist)
    fill_tables<<<(NZ4 + NP4 + 255) / 256, 256, 0, stream>>>((u32x4*)rcnt, (u32x4*)ell16);
    build_tables<<<4 * BB, 256, 0, stream>>>(adds, rcnt, scnt, bmask, list, ell16,
                                             ocntc, ocntr, oentc, oentr);
    hist_rows_kernel<<<NPOS, 512, 0, stream>>>(a_arc, rcnt, list, ell16, hist);
    fixup<<<dim3(BB, 2 * MAXO, SS / 256), 256, 0, stream>>>(a_arc, adds, ocntc, oentc,
                                                            ocntr, oentr, bmask, hist);
    gather_kernel<<<BB * SS, 256, 0, stream>>>(s_arc, pos, hist, out);
}

// Round 18
// 128.402 us; speedup vs baseline: 1.0879x; 1.0254x over previous
//
#include <hip/hip_runtime.h>

#define NPOS 1024
#define BB   32
#define SS   1024
#define ALPHA_C 0.3f
#define OCAP 256      // per-batch overflow capacity per side (mean ~3.7, P(>256)~0)
#define MAXO 16       // overflow entries/batch/side processed by fixup
#define PADPAIR 0x10001000u   // two packed PRE-SHIFTED pads (byte off 4096 = zero slot)
#define SSTRIDE 1026          // floats per S row: 1024 data + zero slot @ [1024] + align
#define NZ4 16656             // uint4s in the zero region (rcnt+scnt+bmask+ocnt*)
#define NP4 16384             // uint4s in ell16 (PADPAIR init)

typedef float    __attribute__((ext_vector_type(2))) f32x2;
typedef float    __attribute__((ext_vector_type(4))) f32x4;
typedef int      __attribute__((ext_vector_type(4))) i32x4;
typedef unsigned __attribute__((ext_vector_type(4))) u32x4;

// ---- K0: one fill kernel: zeros the counter region, PADPAIR-inits the ELL ----
__global__ __launch_bounds__(256) void fill_tables(u32x4* __restrict__ z,
                                                   u32x4* __restrict__ p) {
    const int i = blockIdx.x * 256 + threadIdx.x;
    if (i < NZ4) z[i] = (u32x4){0u, 0u, 0u, 0u};
    else { const int j = i - NZ4; if (j < NP4) p[j] = (u32x4){PADPAIR, PADPAIR, PADPAIR, PADPAIR}; }
}

// ---- K1: whole-chip build (128 blocks x 256): per-(r,b) row lists (W=4 + ovf)
// and per-batch 16-bit column ELL (W=4 + ovf), via global-atomic counters. ----
__global__ __launch_bounds__(256) void build_tables(
    const int* __restrict__ adds, unsigned* __restrict__ rcnt,
    unsigned* __restrict__ scnt, unsigned* __restrict__ bmask,
    ushort* __restrict__ list, ushort* __restrict__ ell16,
    int* __restrict__ ocntc, int* __restrict__ ocntr,
    int* __restrict__ oentc, int* __restrict__ oentr) {
    const int b  = blockIdx.x >> 2;
    const int tg = ((blockIdx.x & 3) << 8) | threadIdx.x;   // p1 / p2 position
    const int c  = adds[b * SS + tg];
    // column side (pre-shifted byte offsets)
    const unsigned slot = atomicAdd(&scnt[b * NPOS + c], 1u);
    if (slot < 4u) {
        ell16[(((size_t)b * 512 + (c & 511)) * 2 + (c >> 9)) * 4 + slot] = (ushort)(tg << 2);
    } else {
        const int o = atomicAdd(&ocntc[b], 1);
        if (o < OCAP) oentc[b * OCAP + o] = (c << 10) | tg;
    }
    // row side (per-(r,b) W=4 list)
    const unsigned rs = atomicAdd(&rcnt[c * BB + b], 1u);
    if (rs < 4u) {
        list[(size_t)c * 128 + b * 4 + rs] = (ushort)tg;
    } else {
        const int o = atomicAdd(&ocntr[b], 1);
        if (o < OCAP) oentr[b * OCAP + o] = (c << 10) | tg;
        atomicOr(&bmask[b * 32 + (tg >> 5)], 1u << (tg & 31));
    }
}

// ---- K2: block per hist row r; iterate ACTIVE batches (~20 of 32).
// DEPTH-3 row pipeline: rows for batch j+3 issued at iter j, consumed at
// j+2's S-write (~1200cy lead > 900cy HBM latency). Pre-sum <=4 rows in
// registers, ds_write ONE combined row S, scatter once via column ELL.
// Writes RAW sums (fixup adds after; gather applies sigmoid). ----
__global__ __launch_bounds__(512) void hist_rows_kernel(
    const float* __restrict__ a, const unsigned* __restrict__ rcnt,
    const ushort* __restrict__ list, const ushort* __restrict__ ell16,
    float* __restrict__ hist) {
    __shared__ float Sbuf[2][SSTRIDE];   // [..][1024] = 0.0f pad slot
    __shared__ ushort lsrc[128];
    __shared__ int   mcnt_s[32];
    __shared__ ushort actb_s[32];
    __shared__ int   na_s;
    const int r = blockIdx.x, t = threadIdx.x;

    if (t < 128) lsrc[t] = list[(size_t)r * 128 + t];
    if (t < 32)  mcnt_s[t] = min((int)rcnt[r * BB + t], 4);
    if (t < 2)   Sbuf[t][1024] = 0.f;
    __syncthreads();
    if (t == 0) {
        int na = 0;
        for (int b = 0; b < 32; ++b) if (mcnt_s[b]) actb_s[na++] = (ushort)b;
        na_s = na;
    }
    __syncthreads();
    const int na = na_s;
    const u32x4* ellv = (const u32x4*)ell16;
    float acc0 = 0.f, acc1 = 0.f;
    u32x4 E = (u32x4){PADPAIR, PADPAIR, PADPAIR, PADPAIR}, F = E;
    f32x2 R0 = (f32x2){0.f, 0.f}, R1 = R0, R2 = R0, R3 = R0;   // batch j+1 rows
    f32x2 T0 = R0, T1 = R0, T2 = R0, T3 = R0;                  // batch j+2 rows
    int mR = 0, mT = 0;

#define ROWP(bb, s) ((const f32x2*)(a + ((((size_t)(bb) << 10) + lsrc[(bb) * 4 + (s)]) << 10)) + t)

    if (na > 0) {
        const int b0 = actb_s[0], m0 = mcnt_s[b0];
        E = ellv[(size_t)b0 * 512 + t];
        f32x2 S = __builtin_nontemporal_load(ROWP(b0, 0));
        if (m0 > 1) S += __builtin_nontemporal_load(ROWP(b0, 1));
        if (m0 > 2) S += __builtin_nontemporal_load(ROWP(b0, 2));
        if (m0 > 3) S += __builtin_nontemporal_load(ROWP(b0, 3));
        ((f32x2*)&Sbuf[0][0])[t] = S;
        if (na > 1) {
            const int b1 = actb_s[1];
            mR = mcnt_s[b1];
            F = ellv[(size_t)b1 * 512 + t];
            R0 = __builtin_nontemporal_load(ROWP(b1, 0));
            if (mR > 1) R1 = __builtin_nontemporal_load(ROWP(b1, 1));
            if (mR > 2) R2 = __builtin_nontemporal_load(ROWP(b1, 2));
            if (mR > 3) R3 = __builtin_nontemporal_load(ROWP(b1, 3));
        }
        if (na > 2) {
            const int b2 = actb_s[2];
            mT = mcnt_s[b2];
            T0 = __builtin_nontemporal_load(ROWP(b2, 0));
            if (mT > 1) T1 = __builtin_nontemporal_load(ROWP(b2, 1));
            if (mT > 2) T2 = __builtin_nontemporal_load(ROWP(b2, 2));
            if (mT > 3) T3 = __builtin_nontemporal_load(ROWP(b2, 3));
        }
    }
    asm volatile("s_waitcnt lgkmcnt(0)" ::: "memory");
    __builtin_amdgcn_s_barrier();

    for (int j = 0; j < na; ++j) {
        // issue row loads for batch j+3 (two full iterations to land)
        f32x2 U0 = (f32x2){0.f, 0.f}, U1 = U0, U2 = U0, U3 = U0;
        int mU = 0;
        if (j + 3 < na) {
            const int b3 = actb_s[j + 3];
            mU = mcnt_s[b3];
            U0 = __builtin_nontemporal_load(ROWP(b3, 0));
            if (mU > 1) U1 = __builtin_nontemporal_load(ROWP(b3, 1));
            if (mU > 2) U2 = __builtin_nontemporal_load(ROWP(b3, 2));
            if (mU > 3) U3 = __builtin_nontemporal_load(ROWP(b3, 3));
        }
        // ELL indices for batch j+2 (consumed at scatter in iter j+2)
        u32x4 TE = (u32x4){PADPAIR, PADPAIR, PADPAIR, PADPAIR};
        if (j + 2 < na) TE = ellv[(size_t)actb_s[j + 2] * 512 + t];
        // pre-sum & write S for batch j+1 (R* issued at iter j-2: ~1200cy lead)
        if (j + 1 < na) {
            f32x2 S = R0;
            if (mR > 1) S += R1;
            if (mR > 2) S += R2;
            if (mR > 3) S += R3;
            ((f32x2*)&Sbuf[(j + 1) & 1][0])[t] = S;
        }
        // scatter batch j from Sbuf[j&1] (8 LDS reads/thread, pre-shifted offsets)
        const char* rb = (const char*)&Sbuf[j & 1][0];
        acc0 += *(const float*)(rb + (E.x & 0xffffu));
        acc0 += *(const float*)(rb + (E.x >> 16));
        acc0 += *(const float*)(rb + (E.y & 0xffffu));
        acc0 += *(const float*)(rb + (E.y >> 16));
        acc1 += *(const float*)(rb + (E.z & 0xffffu));
        acc1 += *(const float*)(rb + (E.z >> 16));
        acc1 += *(const float*)(rb + (E.w & 0xffffu));
        acc1 += *(const float*)(rb + (E.w >> 16));
        // roll pipeline
        E = F; F = TE;
        R0 = T0; R1 = T1; R2 = T2; R3 = T3; mR = mT;
        T0 = U0; T1 = U1; T2 = U2; T3 = U3; mT = mU;
        __builtin_amdgcn_sched_barrier(0);
        asm volatile("s_waitcnt lgkmcnt(0)" ::: "memory");
        __builtin_amdgcn_s_barrier();
    }
#undef ROWP

    const size_t o0 = (size_t)r * NPOS + t;
    hist[o0]       = acc0;     // RAW sums; fixup atomics add after; gather sigmoids
    hist[o0 + 512] = acc1;
}

// ---- K2b: fixups via global atomics AFTER hist_rows (raw domain).
// y<MAXO: col-ovf entry (all p1 EXCEPT row-ovf p1); y>=MAXO: row-ovf (all p2). ----
__global__ __launch_bounds__(256) void fixup(
    const float* __restrict__ a, const int* __restrict__ adds,
    const int* __restrict__ ocntc, const int* __restrict__ oentc,
    const int* __restrict__ ocntr, const int* __restrict__ oentr,
    const unsigned* __restrict__ bmask, float* __restrict__ hist) {
    const int b = blockIdx.x;
    int y = blockIdx.y;
    const int p = blockIdx.z * 256 + threadIdx.x;
    if (y < MAXO) {                    // column overflow: p is p1
        if (y >= ocntc[b]) return;
        const int e = oentc[b * OCAP + y];
        const int c = e >> 10, p2 = e & 1023;
        if ((bmask[b * 32 + (p >> 5)] >> (p & 31)) & 1u) return;  // row-ovf p1 excluded
        const int r = adds[b * SS + p];
        atomicAdd(&hist[(size_t)r * NPOS + c], a[((size_t)(b * SS + p)) * SS + p2]);
    } else {                           // row overflow: p is p2
        y -= MAXO;
        if (y >= ocntr[b]) return;
        const int e = oentr[b * OCAP + y];
        const int r = e >> 10, p1 = e & 1023;
        const int c = adds[b * SS + p];
        atomicAdd(&hist[(size_t)r * NPOS + c], a[((size_t)(b * SS + p1)) * SS + p]);
    }
}

// ---- K3: out = s + 0.3 * sigmoid(hist_raw[pos[b,p1]*1024 + pos[b,p2]]) ----
__global__ __launch_bounds__(256) void gather_kernel(
    const float* __restrict__ s, const int* __restrict__ pos,
    const float* __restrict__ score, float* __restrict__ out) {
    const int row = blockIdx.x;
    const int b   = row >> 10;
    const int*  posb = pos + b * SS;
    const int   base = posb[row & 1023] * NPOS;
    const size_t off = (size_t)row * SS;

    const int t = threadIdx.x;
    f32x4 v = __builtin_nontemporal_load(((const f32x4*)(s + off)) + t);
    i32x4 c = ((const i32x4*)posb)[t];
    const float h0 = score[base + c.x], h1 = score[base + c.y];
    const float h2 = score[base + c.z], h3 = score[base + c.w];
    f32x4 o;
    o.x = v.x + ALPHA_C * (1.f / (1.f + __expf(-h0)));
    o.y = v.y + ALPHA_C * (1.f / (1.f + __expf(-h1)));
    o.z = v.z + ALPHA_C * (1.f / (1.f + __expf(-h2)));
    o.w = v.w + ALPHA_C * (1.f / (1.f + __expf(-h3)));
    __builtin_nontemporal_store(o, ((f32x4*)(out + off)) + t);
}

extern "C" void kernel_launch(void* const* d_in, const int* in_sizes, int n_in,
                              void* d_out, int out_size, void* d_ws, size_t ws_size,
                              hipStream_t stream) {
    const float* s_arc = (const float*)d_in[0];
    const float* a_arc = (const float*)d_in[1];
    const int*   adds  = (const int*)d_in[2];
    const int*   pos   = (const int*)d_in[3];
    float* out  = (float*)d_out;

    // ws layout (bytes):
    // [hist 4MB][rcnt 128K][scnt 128K][bmask 4K][ocntc 128][ocntr 128]
    // [list 256K][ell16 256K][oentc 32K][oentr 32K]  (~4.83MB)
    char* w = (char*)d_ws;
    float*    hist  = (float*)w;                 w += (size_t)NPOS * NPOS * 4;
    unsigned* rcnt  = (unsigned*)w;              w += (size_t)NPOS * BB * 4;
    unsigned* scnt  = (unsigned*)w;              w += (size_t)BB * NPOS * 4;
    unsigned* bmask = (unsigned*)w;              w += (size_t)BB * 32 * 4;
    int*      ocntc = (int*)w;                   w += BB * 4;
    int*      ocntr = (int*)w;                   w += BB * 4;
    ushort*   list  = (ushort*)w;                w += (size_t)NPOS * 128 * 2;
    ushort*   ell16 = (ushort*)w;                w += (size_t)BB * NPOS * 4 * 2;
    int*      oentc = (int*)w;                   w += (size_t)BB * OCAP * 4;
    int*      oentr = (int*)w;

    fill_tables<<<(NZ4 + NP4 + 255) / 256, 256, 0, stream>>>((u32x4*)rcnt, (u32x4*)ell16);
    build_tables<<<4 * BB, 256, 0, stream>>>(adds, rcnt, scnt, bmask, list, ell16,
                                             ocntc, ocntr, oentc, oentr);
    hist_rows_kernel<<<NPOS, 512, 0, stream>>>(a_arc, rcnt, list, ell16, hist);
    fixup<<<dim3(BB, 2 * MAXO, SS / 256), 256, 0, stream>>>(a_arc, adds, ocntc, oentc,
                                                            ocntr, oentr, bmask, hist);
    gather_kernel<<<BB * SS, 256, 0, stream>>>(s_arc, pos, hist, out);
}

// Round 19
// 116.318 us; speedup vs baseline: 1.2010x; 1.1039x over previous
//
#include <hip/hip_runtime.h>

#define NPOS 1024
#define BB   32
#define SS   1024
#define ALPHA_C 0.3f
#define OCAP 256      // per-batch overflow capacity per side (mean ~3.7, P(>256)~0)
#define MAXO 16       // overflow entries/batch/side processed by fixup
#define PADPAIR 0x10001000u   // two packed PRE-SHIFTED pads (byte off 4096 = zero slot)
#define SSTRIDE 1026          // floats per S row: 1024 data + zero slot @ [1024] + align
#define NZ4 16656             // uint4s in the zero region (rcnt+scnt+bmask+ocnt*)
#define NP4 16384             // uint4s in ell16 (PADPAIR init)

typedef float    __attribute__((ext_vector_type(2))) f32x2;
typedef float    __attribute__((ext_vector_type(4))) f32x4;
typedef int      __attribute__((ext_vector_type(4))) i32x4;
typedef unsigned __attribute__((ext_vector_type(4))) u32x4;

// ---- K0: one fill kernel: zeros the counter region, PADPAIR-inits the ELL ----
__global__ __launch_bounds__(256) void fill_tables(u32x4* __restrict__ z,
                                                   u32x4* __restrict__ p) {
    const int i = blockIdx.x * 256 + threadIdx.x;
    if (i < NZ4) z[i] = (u32x4){0u, 0u, 0u, 0u};
    else { const int j = i - NZ4; if (j < NP4) p[j] = (u32x4){PADPAIR, PADPAIR, PADPAIR, PADPAIR}; }
}

// ---- K1: whole-chip build (128 blocks x 256): per-(r,b) row lists (W=4 + ovf)
// and per-batch 16-bit column ELL (W=4 + ovf), via global-atomic counters. ----
__global__ __launch_bounds__(256) void build_tables(
    const int* __restrict__ adds, unsigned* __restrict__ rcnt,
    unsigned* __restrict__ scnt, unsigned* __restrict__ bmask,
    ushort* __restrict__ list, ushort* __restrict__ ell16,
    int* __restrict__ ocntc, int* __restrict__ ocntr,
    int* __restrict__ oentc, int* __restrict__ oentr) {
    const int b  = blockIdx.x >> 2;
    const int tg = ((blockIdx.x & 3) << 8) | threadIdx.x;   // p1 / p2 position
    const int c  = adds[b * SS + tg];
    // column side (pre-shifted byte offsets)
    const unsigned slot = atomicAdd(&scnt[b * NPOS + c], 1u);
    if (slot < 4u) {
        ell16[(((size_t)b * 512 + (c & 511)) * 2 + (c >> 9)) * 4 + slot] = (ushort)(tg << 2);
    } else {
        const int o = atomicAdd(&ocntc[b], 1);
        if (o < OCAP) oentc[b * OCAP + o] = (c << 10) | tg;
    }
    // row side (per-(r,b) W=4 list)
    const unsigned rs = atomicAdd(&rcnt[c * BB + b], 1u);
    if (rs < 4u) {
        list[(size_t)c * 128 + b * 4 + rs] = (ushort)tg;
    } else {
        const int o = atomicAdd(&ocntr[b], 1);
        if (o < OCAP) oentr[b * OCAP + o] = (c << 10) | tg;
        atomicOr(&bmask[b * 32 + (tg >> 5)], 1u << (tg & 31));
    }
}

// ---- K2: block per hist row r; iterate ACTIVE batches (~20 of 32).
// DEPTH-3 row pipeline: rows for batch j+3 issued at iter j, consumed at
// j+2's S-write (~1200cy lead > 900cy HBM latency). Pre-sum <=4 rows in
// registers, ds_write ONE combined row S, scatter once via column ELL.
// Writes RAW sums (fixup adds after; gather applies sigmoid). ----
__global__ __launch_bounds__(512) void hist_rows_kernel(
    const float* __restrict__ a, const unsigned* __restrict__ rcnt,
    const ushort* __restrict__ list, const ushort* __restrict__ ell16,
    float* __restrict__ hist) {
    __shared__ float Sbuf[2][SSTRIDE];   // [..][1024] = 0.0f pad slot
    __shared__ ushort lsrc[128];
    __shared__ int   mcnt_s[32];
    __shared__ ushort actb_s[32];
    __shared__ int   na_s;
    const int r = blockIdx.x, t = threadIdx.x;

    if (t < 128) lsrc[t] = list[(size_t)r * 128 + t];
    if (t < 32)  mcnt_s[t] = min((int)rcnt[r * BB + t], 4);
    if (t < 2)   Sbuf[t][1024] = 0.f;
    __syncthreads();
    if (t == 0) {
        int na = 0;
        for (int b = 0; b < 32; ++b) if (mcnt_s[b]) actb_s[na++] = (ushort)b;
        na_s = na;
    }
    __syncthreads();
    const int na = na_s;
    const u32x4* ellv = (const u32x4*)ell16;
    float acc0 = 0.f, acc1 = 0.f;
    u32x4 E = (u32x4){PADPAIR, PADPAIR, PADPAIR, PADPAIR}, F = E;
    f32x2 R0 = (f32x2){0.f, 0.f}, R1 = R0, R2 = R0, R3 = R0;   // batch j+1 rows
    f32x2 T0 = R0, T1 = R0, T2 = R0, T3 = R0;                  // batch j+2 rows
    int mR = 0, mT = 0;

#define ROWP(bb, s) ((const f32x2*)(a + ((((size_t)(bb) << 10) + lsrc[(bb) * 4 + (s)]) << 10)) + t)

    if (na > 0) {
        const int b0 = actb_s[0], m0 = mcnt_s[b0];
        E = ellv[(size_t)b0 * 512 + t];
        f32x2 S = __builtin_nontemporal_load(ROWP(b0, 0));
        if (m0 > 1) S += __builtin_nontemporal_load(ROWP(b0, 1));
        if (m0 > 2) S += __builtin_nontemporal_load(ROWP(b0, 2));
        if (m0 > 3) S += __builtin_nontemporal_load(ROWP(b0, 3));
        ((f32x2*)&Sbuf[0][0])[t] = S;
        if (na > 1) {
            const int b1 = actb_s[1];
            mR = mcnt_s[b1];
            F = ellv[(size_t)b1 * 512 + t];
            R0 = __builtin_nontemporal_load(ROWP(b1, 0));
            if (mR > 1) R1 = __builtin_nontemporal_load(ROWP(b1, 1));
            if (mR > 2) R2 = __builtin_nontemporal_load(ROWP(b1, 2));
            if (mR > 3) R3 = __builtin_nontemporal_load(ROWP(b1, 3));
        }
        if (na > 2) {
            const int b2 = actb_s[2];
            mT = mcnt_s[b2];
            T0 = __builtin_nontemporal_load(ROWP(b2, 0));
            if (mT > 1) T1 = __builtin_nontemporal_load(ROWP(b2, 1));
            if (mT > 2) T2 = __builtin_nontemporal_load(ROWP(b2, 2));
            if (mT > 3) T3 = __builtin_nontemporal_load(ROWP(b2, 3));
        }
    }
    asm volatile("s_waitcnt lgkmcnt(0)" ::: "memory");
    __builtin_amdgcn_s_barrier();

    for (int j = 0; j < na; ++j) {
        // issue row loads for batch j+3 (two full iterations to land)
        f32x2 U0 = (f32x2){0.f, 0.f}, U1 = U0, U2 = U0, U3 = U0;
        int mU = 0;
        if (j + 3 < na) {
            const int b3 = actb_s[j + 3];
            mU = mcnt_s[b3];
            U0 = __builtin_nontemporal_load(ROWP(b3, 0));
            if (mU > 1) U1 = __builtin_nontemporal_load(ROWP(b3, 1));
            if (mU > 2) U2 = __builtin_nontemporal_load(ROWP(b3, 2));
            if (mU > 3) U3 = __builtin_nontemporal_load(ROWP(b3, 3));
        }
        // ELL indices for batch j+2 (consumed at scatter in iter j+2)
        u32x4 TE = (u32x4){PADPAIR, PADPAIR, PADPAIR, PADPAIR};
        if (j + 2 < na) TE = ellv[(size_t)actb_s[j + 2] * 512 + t];
        // pre-sum & write S for batch j+1 (R* issued at iter j-2: ~1200cy lead)
        if (j + 1 < na) {
            f32x2 S = R0;
            if (mR > 1) S += R1;
            if (mR > 2) S += R2;
            if (mR > 3) S += R3;
            ((f32x2*)&Sbuf[(j + 1) & 1][0])[t] = S;
        }
        // scatter batch j from Sbuf[j&1] (8 LDS reads/thread, pre-shifted offsets)
        const char* rb = (const char*)&Sbuf[j & 1][0];
        acc0 += *(const float*)(rb + (E.x & 0xffffu));
        acc0 += *(const float*)(rb + (E.x >> 16));
        acc0 += *(const float*)(rb + (E.y & 0xffffu));
        acc0 += *(const float*)(rb + (E.y >> 16));
        acc1 += *(const float*)(rb + (E.z & 0xffffu));
        acc1 += *(const float*)(rb + (E.z >> 16));
        acc1 += *(const float*)(rb + (E.w & 0xffffu));
        acc1 += *(const float*)(rb + (E.w >> 16));
        // roll pipeline
        E = F; F = TE;
        R0 = T0; R1 = T1; R2 = T2; R3 = T3; mR = mT;
        T0 = U0; T1 = U1; T2 = U2; T3 = U3; mT = mU;
        __builtin_amdgcn_sched_barrier(0);
        asm volatile("s_waitcnt lgkmcnt(0)" ::: "memory");
        __builtin_amdgcn_s_barrier();
    }
#undef ROWP

    const size_t o0 = (size_t)r * NPOS + t;
    hist[o0]       = acc0;     // RAW sums; fixup atomics add after; gather sigmoids
    hist[o0 + 512] = acc1;
}

// ---- K2b: fixups via global atomics AFTER hist_rows (raw domain).
// y<MAXO: col-ovf entry (all p1 EXCEPT row-ovf p1); y>=MAXO: row-ovf (all p2). ----
__global__ __launch_bounds__(256) void fixup(
    const float* __restrict__ a, const int* __restrict__ adds,
    const int* __restrict__ ocntc, const int* __restrict__ oentc,
    const int* __restrict__ ocntr, const int* __restrict__ oentr,
    const unsigned* __restrict__ bmask, float* __restrict__ hist) {
    const int b = blockIdx.x;
    int y = blockIdx.y;
    const int p = blockIdx.z * 256 + threadIdx.x;
    if (y < MAXO) {                    // column overflow: p is p1
        if (y >= ocntc[b]) return;
        const int e = oentc[b * OCAP + y];
        const int c = e >> 10, p2 = e & 1023;
        if ((bmask[b * 32 + (p >> 5)] >> (p & 31)) & 1u) return;  // row-ovf p1 excluded
        const int r = adds[b * SS + p];
        atomicAdd(&hist[(size_t)r * NPOS + c], a[((size_t)(b * SS + p)) * SS + p2]);
    } else {                           // row overflow: p is p2
        y -= MAXO;
        if (y >= ocntr[b]) return;
        const int e = oentr[b * OCAP + y];
        const int r = e >> 10, p1 = e & 1023;
        const int c = adds[b * SS + p];
        atomicAdd(&hist[(size_t)r * NPOS + c], a[((size_t)(b * SS + p1)) * SS + p]);
    }
}

// ---- K3: out = s + 0.3 * sigmoid(score_row[pos[b,p2]]), score row staged in
// LDS: base = pos[b,p1]*1024 is WAVE-UNIFORM per block, so 4 coalesced wave
// loads stage the 4KB row; the 4 random reads/thread then hit LDS (~10cy)
// instead of serialized L1 gathers (~64cy/wave-instr). ----
__global__ __launch_bounds__(256) void gather_kernel(
    const float* __restrict__ s, const int* __restrict__ pos,
    const float* __restrict__ score, float* __restrict__ out) {
    __shared__ float srow[NPOS];
    const int row = blockIdx.x;
    const int b   = row >> 10;
    const int*  posb = pos + b * SS;
    const int   base = posb[row & 1023] * NPOS;
    const size_t off = (size_t)row * SS;
    const int t = threadIdx.x;

    // stage the score row (coalesced, L2/L3-hot) + issue stream loads
    const f32x4 sc = ((const f32x4*)(score + base))[t];
    f32x4 v = __builtin_nontemporal_load(((const f32x4*)(s + off)) + t);
    i32x4 c = ((const i32x4*)posb)[t];
    ((f32x4*)srow)[t] = sc;
    __syncthreads();

    const float h0 = srow[c.x], h1 = srow[c.y];
    const float h2 = srow[c.z], h3 = srow[c.w];
    f32x4 o;
    o.x = v.x + ALPHA_C * (1.f / (1.f + __expf(-h0)));
    o.y = v.y + ALPHA_C * (1.f / (1.f + __expf(-h1)));
    o.z = v.z + ALPHA_C * (1.f / (1.f + __expf(-h2)));
    o.w = v.w + ALPHA_C * (1.f / (1.f + __expf(-h3)));
    __builtin_nontemporal_store(o, ((f32x4*)(out + off)) + t);
}

extern "C" void kernel_launch(void* const* d_in, const int* in_sizes, int n_in,
                              void* d_out, int out_size, void* d_ws, size_t ws_size,
                              hipStream_t stream) {
    const float* s_arc = (const float*)d_in[0];
    const float* a_arc = (const float*)d_in[1];
    const int*   adds  = (const int*)d_in[2];
    const int*   pos   = (const int*)d_in[3];
    float* out  = (float*)d_out;

    // ws layout (bytes):
    // [hist 4MB][rcnt 128K][scnt 128K][bmask 4K][ocntc 128][ocntr 128]
    // [list 256K][ell16 256K][oentc 32K][oentr 32K]  (~4.83MB)
    char* w = (char*)d_ws;
    float*    hist  = (float*)w;                 w += (size_t)NPOS * NPOS * 4;
    unsigned* rcnt  = (unsigned*)w;              w += (size_t)NPOS * BB * 4;
    unsigned* scnt  = (unsigned*)w;              w += (size_t)BB * NPOS * 4;
    unsigned* bmask = (unsigned*)w;              w += (size_t)BB * 32 * 4;
    int*      ocntc = (int*)w;                   w += BB * 4;
    int*      ocntr = (int*)w;                   w += BB * 4;
    ushort*   list  = (ushort*)w;                w += (size_t)NPOS * 128 * 2;
    ushort*   ell16 = (ushort*)w;                w += (size_t)BB * NPOS * 4 * 2;
    int*      oentc = (int*)w;                   w += (size_t)BB * OCAP * 4;
    int*      oentr = (int*)w;

    fill_tables<<<(NZ4 + NP4 + 255) / 256, 256, 0, stream>>>((u32x4*)rcnt, (u32x4*)ell16);
    build_tables<<<4 * BB, 256, 0, stream>>>(adds, rcnt, scnt, bmask, list, ell16,
                                             ocntc, ocntr, oentc, oentr);
    hist_rows_kernel<<<NPOS, 512, 0, stream>>>(a_arc, rcnt, list, ell16, hist);
    fixup<<<dim3(BB, 2 * MAXO, SS / 256), 256, 0, stream>>>(a_arc, adds, ocntc, oentc,
                                                            ocntr, oentr, bmask, hist);
    gather_kernel<<<BB * SS, 256, 0, stream>>>(s_arc, pos, hist, out);
}